// Round 5
// baseline (535.390 us; speedup 1.0000x reference)
//
#include <hip/hip_runtime.h>
#include <hip/hip_bf16.h>

// RolePositionBiasedAttention: B=16384, N=10, D=256, H=8, DH=32
// prep_wt (once) -> fused_all: per block 8 batches (80 rows), 4 head-pair passes:
//   QKV GEMM (MFMA, acc_s) -> epi (q,k swizzled strip; v transposed Vt) -> barrier
//   -> attn per wave: QK mfma_16x16x32 + shuffle-softmax + PV mfma_32x32x16,
//      O overwrites q-region -> barrier -> WO mfma accumulates acc_o -> barrier.
// Z read once, out written once. No big per-thread arrays besides acc_o/acc_s.

typedef __attribute__((ext_vector_type(8))) short bf16x8;
typedef __attribute__((ext_vector_type(4))) float f32x4;
typedef __attribute__((ext_vector_type(16))) float f32x16;

__device__ __forceinline__ unsigned short f2bf(float f) {
  union { __hip_bfloat16 h; unsigned short u; } cv;
  cv.h = __float2bfloat16(f);
  return cv.u;
}
__device__ __forceinline__ float bf2f(unsigned int u) { return __uint_as_float(u << 16); }

// ---------------- prep: WT[w][n][k] = bf16(W[k][n]), w in {Q,K,V,O} ----------------
__global__ void prep_wt_kernel(const float* __restrict__ WQ, const float* __restrict__ WK,
                               const float* __restrict__ WV, const float* __restrict__ WO,
                               __hip_bfloat16* __restrict__ wt) {
  const int k = blockIdx.x;      // 0..255
  const int n = threadIdx.x;     // 0..255
  wt[0 * 65536 + n * 256 + k] = __float2bfloat16(WQ[k * 256 + n]);
  wt[1 * 65536 + n * 256 + k] = __float2bfloat16(WK[k * 256 + n]);
  wt[2 * 65536 + n * 256 + k] = __float2bfloat16(WV[k * 256 + n]);
  wt[3 * 65536 + n * 256 + k] = __float2bfloat16(WO[k * 256 + n]);
}

// LDS layout (bytes):
#define AS_OFF 0        // [80][512]  Z bf16, 32 chunks/row, chunk c at (c^(row&7))*16
#define SP_OFF 40960    // [80][256]  q/O region 0..127 (8 swz chunks) | k region 128..255
#define VT_OFF 61440    // [64 d][8 b][16 j] bf16, d-stride 272 B (j 10..15 zeroed once)
#define PT_OFF 78848    // 4 waves x 320 B: P tile rows 0..9 x 16 j (bf16)
#define RL_OFF 80128    // 80 roles (u8)
#define BP_OFF 80208    // 800 bias values (bf16)
#define LDS_SZ 81808
#define VT_STR 272

__global__ __launch_bounds__(256, 2) void fused_all_kernel(
    const float* __restrict__ Z, const __hip_bfloat16* __restrict__ wt,
    const int* __restrict__ roles, const float* __restrict__ Bp,
    float* __restrict__ out)
{
  __shared__ __align__(16) char lds[LDS_SZ];
  unsigned char* rl = (unsigned char*)(lds + RL_OFF);
  unsigned short* bp = (unsigned short*)(lds + BP_OFF);

  const int t = threadIdx.x;
  const int lane = t & 63;
  const int wv = t >> 6;
  const int g = lane >> 4, cx = lane & 15;
  const int blk = blockIdx.x;
  const size_t r0 = (size_t)blk * 80;

  // ---- one-time staging ----
  if (t < 80) rl[t] = (unsigned char)roles[r0 + t];
  if (t < 200) {
    float4 f = ((const float4*)Bp)[t];
    bp[t * 4 + 0] = f2bf(f.x); bp[t * 4 + 1] = f2bf(f.y);
    bp[t * 4 + 2] = f2bf(f.z); bp[t * 4 + 3] = f2bf(f.w);
  }
  #pragma unroll
  for (int z = 0; z < 17; ++z)              // zero all of Vt (17408 B = 4352 dwords)
    ((unsigned int*)(lds + VT_OFF))[z * 256 + t] = 0u;

  // ---- stage Z tile -> As (fp32 -> bf16, swizzled 16B chunks) ----
  #pragma unroll
  for (int c = 0; c < 10; ++c) {
    const int idx = c * 256 + t;            // (row, chunk) over 80x32
    const int row = idx >> 5, ch = idx & 31;
    const float* src = Z + (r0 + row) * 256 + ch * 8;
    float4 f0 = *(const float4*)(src);
    float4 f1 = *(const float4*)(src + 4);
    union { bf16x8 v; unsigned short u[8]; } pk;
    pk.u[0] = f2bf(f0.x); pk.u[1] = f2bf(f0.y);
    pk.u[2] = f2bf(f0.z); pk.u[3] = f2bf(f0.w);
    pk.u[4] = f2bf(f1.x); pk.u[5] = f2bf(f1.y);
    pk.u[6] = f2bf(f1.z); pk.u[7] = f2bf(f1.w);
    *(bf16x8*)(lds + AS_OFF + row * 512 + ((ch ^ (row & 7)) * 16)) = pk.v;
  }
  __syncthreads();

  f32x16 zero16;
  #pragma unroll
  for (int r = 0; r < 16; ++r) zero16[r] = 0.f;

  f32x4 acc_o[5][4];
  #pragma unroll
  for (int a = 0; a < 5; ++a)
    #pragma unroll
    for (int b = 0; b < 4; ++b) acc_o[a][b] = (f32x4){0.f, 0.f, 0.f, 0.f};

  #pragma unroll 1
  for (int p = 0; p < 4; ++p) {
    // ======== QKV strip GEMM: 80 x 192 (q|k|v for heads 2p,2p+1) ========
    f32x4 acc_s[5][3];
    #pragma unroll
    for (int mi = 0; mi < 5; ++mi)
      #pragma unroll
      for (int nf = 0; nf < 3; ++nf) acc_s[mi][nf] = (f32x4){0.f, 0.f, 0.f, 0.f};
    {
      const __hip_bfloat16* bptr[3];
      #pragma unroll
      for (int nf = 0; nf < 3; ++nf) {
        const int f = wv * 3 + nf;            // 0..11
        const int mf = f >> 2;                // 0=Q,1=K,2=V
        const int ncol = p * 64 + (f & 3) * 16;
        bptr[nf] = wt + mf * 65536 + (ncol + cx) * 256 + g * 8;
      }
      #pragma unroll
      for (int kk = 0; kk < 8; ++kk) {
        bf16x8 bfr[3];
        #pragma unroll
        for (int nf = 0; nf < 3; ++nf) bfr[nf] = *(const bf16x8*)(bptr[nf] + kk * 32);
        bf16x8 afr[5];
        #pragma unroll
        for (int mi = 0; mi < 5; ++mi) {
          const int row = mi * 16 + cx;
          const int ch = (kk * 4 + g) ^ (row & 7);
          afr[mi] = *(const bf16x8*)(lds + AS_OFF + row * 512 + ch * 16);
        }
        #pragma unroll
        for (int mi = 0; mi < 5; ++mi)
          #pragma unroll
          for (int nf = 0; nf < 3; ++nf)
            acc_s[mi][nf] = __builtin_amdgcn_mfma_f32_16x16x32_bf16(afr[mi], bfr[nf], acc_s[mi][nf], 0, 0, 0);
      }
    }
    // ======== epilogue: q,k -> swizzled strip; v -> Vt transposed ========
    #pragma unroll
    for (int mi = 0; mi < 5; ++mi)
      #pragma unroll
      for (int nf = 0; nf < 3; ++nf) {
        const int col = wv * 48 + nf * 16 + cx;     // 0..191 (uniform branch per wv,nf)
        #pragma unroll
        for (int jj = 0; jj < 4; ++jj) {
          const int row = mi * 16 + g * 4 + jj;
          const unsigned short val = f2bf(acc_s[mi][nf][jj]);
          if (col < 64) {
            *(unsigned short*)(lds + SP_OFF + row * 256 +
                (((col >> 3) ^ (row & 7)) * 16) + (col & 7) * 2) = val;
          } else if (col < 128) {
            const int c = (col - 64) >> 3;
            *(unsigned short*)(lds + SP_OFF + row * 256 + 128 +
                ((c ^ (row & 7)) * 16) + (col & 7) * 2) = val;
          } else {
            const int vd = col - 128;                 // 0..63 = hh*32+d
            const int rb = (row * 205) >> 11;         // row/10 (row<80)
            const int jr = row - rb * 10;
            *(unsigned short*)(lds + VT_OFF + vd * VT_STR + rb * 32 + jr * 2) = val;
          }
        }
      }
    __syncthreads();

    // ======== attention: each wave owns 4 problems (b = 2wv,2wv+1; hh = 0,1) ========
    {
      const int m = lane & 15;          // QK: A-row block (i) / B-col (j)
      const int kq = lane >> 4;         // 0..3
      const int kg = lane >> 5;         // 0..1
      const int dcol = lane & 31;
      float pn[4][4];

      // --- QK + bias + shuffle-softmax, all 4 problems ---
      #pragma unroll
      for (int q = 0; q < 4; ++q) {
        const int b = wv * 2 + (q >> 1);
        const int hh = q & 1;
        const int h = p * 2 + hh;
        const int arow = b * 10 + m;                       // >=80 for b=7,m>=10: garbage, discarded
        const int chq = ((hh * 4 + kq) ^ (arow & 7)) * 16;
        bf16x8 aq = *(const bf16x8*)(lds + SP_OFF + arow * 256 + chq);
        bf16x8 bk = *(const bf16x8*)(lds + SP_OFF + arow * 256 + 128 + chq);
        f32x4 S = (f32x4){0.f, 0.f, 0.f, 0.f};
        S = __builtin_amdgcn_mfma_f32_16x16x32_bf16(aq, bk, S, 0, 0, 0);
        const int rj = rl[min(arow, 79)];
        #pragma unroll
        for (int jj = 0; jj < 4; ++jj) {
          const int i = kq * 4 + jj;
          const int ri = rl[min(b * 10 + i, 79)];
          float s = S[jj] * 0.17677669529663687f + bf2f(bp[h * 100 + ri * 10 + rj]);
          if (m >= 10) s = -1e30f;                         // mask invalid j
          float mx = s;
          mx = fmaxf(mx, __shfl_xor(mx, 1));
          mx = fmaxf(mx, __shfl_xor(mx, 2));
          mx = fmaxf(mx, __shfl_xor(mx, 4));
          mx = fmaxf(mx, __shfl_xor(mx, 8));
          float e = __expf(s - mx);                        // masked -> exactly 0
          float sm = e;
          sm += __shfl_xor(sm, 1);
          sm += __shfl_xor(sm, 2);
          sm += __shfl_xor(sm, 4);
          sm += __shfl_xor(sm, 8);
          pn[q][jj] = e / sm;
        }
      }
      // --- P-store + PV + O-store, per problem ---
      #pragma unroll
      for (int q = 0; q < 4; ++q) {
        const int b = wv * 2 + (q >> 1);
        const int hh = q & 1;
        #pragma unroll
        for (int jj = 0; jj < 4; ++jj) {
          const int i = kq * 4 + jj;
          if (i < 10)
            *(unsigned short*)(lds + PT_OFF + wv * 320 + i * 32 + m * 2) = f2bf(pn[q][jj]);
        }
        // PV: O[i][d] = sum_j P[i][j] * V[b*10+j][hh*32+d]  (K=16, j>=10 -> P=0)
        bf16x8 pa = *(const bf16x8*)(lds + PT_OFF + wv * 320 + dcol * 32 + kg * 16);
        bf16x8 vb = *(const bf16x8*)(lds + VT_OFF + (hh * 32 + dcol) * VT_STR + b * 32 + kg * 16);
        f32x16 O = __builtin_amdgcn_mfma_f32_32x32x16_bf16(pa, vb, zero16, 0, 0, 0);
        #pragma unroll
        for (int r = 0; r < 6; ++r) {                      // valid output rows only
          const int i = (r & 3) + 8 * (r >> 2) + 4 * kg;
          if (r < 4 || kg == 0) {
            const int row = b * 10 + i;
            const int ch2 = ((hh * 4 + (dcol >> 3)) ^ (row & 7)) * 16;
            *(unsigned short*)(lds + SP_OFF + row * 256 + ch2 + (dcol & 7) * 2) = f2bf(O[r]);
          }
        }
      }
    }
    __syncthreads();

    // ======== WO: acc_o += O_strip(80x64) x WO[p*64 .. p*64+63][:] ========
    {
      const __hip_bfloat16* WOT = wt + 3 * 65536;
      #pragma unroll
      for (int kk = 0; kk < 2; ++kk) {
        bf16x8 bw[4];
        #pragma unroll
        for (int nf = 0; nf < 4; ++nf) {
          const int n = wv * 64 + nf * 16 + cx;
          bw[nf] = *(const bf16x8*)(WOT + n * 256 + p * 64 + kk * 32 + g * 8);
        }
        bf16x8 aw[5];
        #pragma unroll
        for (int mi = 0; mi < 5; ++mi) {
          const int row = mi * 16 + cx;
          const int ch = (kk * 4 + g) ^ (row & 7);
          aw[mi] = *(const bf16x8*)(lds + SP_OFF + row * 256 + ch * 16);
        }
        #pragma unroll
        for (int mi = 0; mi < 5; ++mi)
          #pragma unroll
          for (int nf = 0; nf < 4; ++nf)
            acc_o[mi][nf] = __builtin_amdgcn_mfma_f32_16x16x32_bf16(aw[mi], bw[nf], acc_o[mi][nf], 0, 0, 0);
      }
    }
    __syncthreads();
  }

  // ---- final out epilogue (fp32) ----
  #pragma unroll
  for (int mi = 0; mi < 5; ++mi)
    #pragma unroll
    for (int nf = 0; nf < 4; ++nf)
      #pragma unroll
      for (int jj = 0; jj < 4; ++jj) {
        const size_t row = r0 + mi * 16 + g * 4 + jj;
        const int col = wv * 64 + nf * 16 + cx;
        out[row * 256 + col] = acc_o[mi][nf][jj];
      }
}

extern "C" void kernel_launch(void* const* d_in, const int* in_sizes, int n_in,
                              void* d_out, int out_size, void* d_ws, size_t ws_size,
                              hipStream_t stream)
{
  const float* Z     = (const float*)d_in[0];
  const int*   roles = (const int*)d_in[1];
  const float* WQ    = (const float*)d_in[2];
  const float* WK    = (const float*)d_in[3];
  const float* WV    = (const float*)d_in[4];
  const float* WO    = (const float*)d_in[5];
  const float* Bp    = (const float*)d_in[6];
  float* out = (float*)d_out;

  __hip_bfloat16* wt = (__hip_bfloat16*)d_ws;   // 512 KiB

  prep_wt_kernel<<<256, 256, 0, stream>>>(WQ, WK, WV, WO, wt);
  fused_all_kernel<<<2048, 256, 0, stream>>>(Z, wt, roles, Bp, out);
}

// Round 6
// 393.928 us; speedup vs baseline: 1.3591x; 1.3591x over previous
//
#include <hip/hip_runtime.h>
#include <hip/hip_bf16.h>

// RolePositionBiasedAttention: B=16384, N=10, D=256, H=8, DH=32
// prep_wt (once) -> fused_qkv_attn (QKV GEMM + MFMA attention, writes attn_out bf16)
//                -> gemm_wo (bf16 MFMA, fp32 out)
// No persistent cross-pass register accumulator => no spills (round-4/5 lesson).

typedef __attribute__((ext_vector_type(8))) short bf16x8;
typedef __attribute__((ext_vector_type(4))) float f32x4;
typedef __attribute__((ext_vector_type(16))) float f32x16;

__device__ __forceinline__ unsigned short f2bf(float f) {
  union { __hip_bfloat16 h; unsigned short u; } cv;
  cv.h = __float2bfloat16(f);
  return cv.u;
}
__device__ __forceinline__ float bf2f(unsigned int u) { return __uint_as_float(u << 16); }

// ---------------- prep: WT[w][n][k] = bf16(W[k][n]), w in {Q,K,V,O} ----------------
__global__ void prep_wt_kernel(const float* __restrict__ WQ, const float* __restrict__ WK,
                               const float* __restrict__ WV, const float* __restrict__ WO,
                               __hip_bfloat16* __restrict__ wt) {
  const int k = blockIdx.x;      // 0..255
  const int n = threadIdx.x;     // 0..255
  wt[0 * 65536 + n * 256 + k] = __float2bfloat16(WQ[k * 256 + n]);
  wt[1 * 65536 + n * 256 + k] = __float2bfloat16(WK[k * 256 + n]);
  wt[2 * 65536 + n * 256 + k] = __float2bfloat16(WV[k * 256 + n]);
  wt[3 * 65536 + n * 256 + k] = __float2bfloat16(WO[k * 256 + n]);
}

// LDS layout (bytes):
#define AS_OFF 0        // [80][512]  Z bf16, 32 chunks/row, chunk c at (c^(row&7))*16
#define SP_OFF 40960    // [80][256]  q region 0..127 (8 swz chunks) | k region 128..255
#define VT_OFF 61440    // [64 d][8 b][16 j] bf16, d-stride 272 B (j 10..15 zeroed once)
#define PT_OFF 78848    // 4 waves x 320 B: P tile rows 0..9 x 16 j (bf16)
#define RL_OFF 80128    // 80 roles (u8)
#define BP_OFF 80208    // 800 bias values (bf16)
#define LDS_SZ 81808
#define VT_STR 272

__global__ __launch_bounds__(256, 2) void fused_qkv_attn_kernel(
    const float* __restrict__ Z, const __hip_bfloat16* __restrict__ wt,
    const int* __restrict__ roles, const float* __restrict__ Bp,
    __hip_bfloat16* __restrict__ attn_out)
{
  __shared__ __align__(16) char lds[LDS_SZ];
  unsigned char* rl = (unsigned char*)(lds + RL_OFF);
  unsigned short* bp = (unsigned short*)(lds + BP_OFF);

  const int t = threadIdx.x;
  const int lane = t & 63;
  const int wv = t >> 6;
  const int g = lane >> 4, cx = lane & 15;
  const int blk = blockIdx.x;
  const size_t c0 = (size_t)blk * 80;        // chunk-local row base

  // ---- one-time staging ----
  if (t < 80) rl[t] = (unsigned char)roles[c0 + t];
  if (t < 200) {
    float4 f = ((const float4*)Bp)[t];
    bp[t * 4 + 0] = f2bf(f.x); bp[t * 4 + 1] = f2bf(f.y);
    bp[t * 4 + 2] = f2bf(f.z); bp[t * 4 + 3] = f2bf(f.w);
  }
  #pragma unroll
  for (int z = 0; z < 17; ++z)               // zero Vt (incl. j-pad)
    ((unsigned int*)(lds + VT_OFF))[z * 256 + t] = 0u;

  // ---- stage Z tile -> As (fp32 -> bf16, swizzled 16B chunks) ----
  #pragma unroll
  for (int c = 0; c < 10; ++c) {
    const int idx = c * 256 + t;             // (row, chunk) over 80x32
    const int row = idx >> 5, ch = idx & 31;
    const float* src = Z + (c0 + row) * 256 + ch * 8;
    float4 f0 = *(const float4*)(src);
    float4 f1 = *(const float4*)(src + 4);
    union { bf16x8 v; unsigned short u[8]; } pk;
    pk.u[0] = f2bf(f0.x); pk.u[1] = f2bf(f0.y);
    pk.u[2] = f2bf(f0.z); pk.u[3] = f2bf(f0.w);
    pk.u[4] = f2bf(f1.x); pk.u[5] = f2bf(f1.y);
    pk.u[6] = f2bf(f1.z); pk.u[7] = f2bf(f1.w);
    *(bf16x8*)(lds + AS_OFF + row * 512 + ((ch ^ (row & 7)) * 16)) = pk.v;
  }
  __syncthreads();

  #pragma unroll 1
  for (int p = 0; p < 4; ++p) {
    // ======== QKV strip GEMM: 80 x 192 (q|k|v for heads 2p,2p+1) ========
    f32x4 acc_s[5][3];
    #pragma unroll
    for (int mi = 0; mi < 5; ++mi)
      #pragma unroll
      for (int nf = 0; nf < 3; ++nf) acc_s[mi][nf] = (f32x4){0.f, 0.f, 0.f, 0.f};
    {
      const __hip_bfloat16* bptr[3];
      #pragma unroll
      for (int nf = 0; nf < 3; ++nf) {
        const int f = wv * 3 + nf;             // 0..11
        const int mf = f >> 2;                 // 0=Q,1=K,2=V
        const int ncol = p * 64 + (f & 3) * 16;
        bptr[nf] = wt + mf * 65536 + (ncol + cx) * 256 + g * 8;
      }
      #pragma unroll
      for (int kk = 0; kk < 8; ++kk) {
        bf16x8 bfr[3];
        #pragma unroll
        for (int nf = 0; nf < 3; ++nf) bfr[nf] = *(const bf16x8*)(bptr[nf] + kk * 32);
        bf16x8 afr[5];
        #pragma unroll
        for (int mi = 0; mi < 5; ++mi) {
          const int row = mi * 16 + cx;
          const int ch = (kk * 4 + g) ^ (row & 7);
          afr[mi] = *(const bf16x8*)(lds + AS_OFF + row * 512 + ch * 16);
        }
        #pragma unroll
        for (int mi = 0; mi < 5; ++mi)
          #pragma unroll
          for (int nf = 0; nf < 3; ++nf)
            acc_s[mi][nf] = __builtin_amdgcn_mfma_f32_16x16x32_bf16(afr[mi], bfr[nf], acc_s[mi][nf], 0, 0, 0);
      }
    }
    // ======== epilogue: q,k -> swizzled strip; v -> Vt transposed ========
    #pragma unroll
    for (int mi = 0; mi < 5; ++mi)
      #pragma unroll
      for (int nf = 0; nf < 3; ++nf) {
        const int col = wv * 48 + nf * 16 + cx;   // 0..191 (uniform per wv,nf)
        #pragma unroll
        for (int jj = 0; jj < 4; ++jj) {
          const int row = mi * 16 + g * 4 + jj;
          const unsigned short val = f2bf(acc_s[mi][nf][jj]);
          if (col < 64) {
            *(unsigned short*)(lds + SP_OFF + row * 256 +
                (((col >> 3) ^ (row & 7)) * 16) + (col & 7) * 2) = val;
          } else if (col < 128) {
            const int c = (col - 64) >> 3;
            *(unsigned short*)(lds + SP_OFF + row * 256 + 128 +
                ((c ^ (row & 7)) * 16) + (col & 7) * 2) = val;
          } else {
            const int vd = col - 128;               // 0..63 = hh*32+d
            const int rb = (row * 205) >> 11;       // row/10 (row<80)
            const int jr = row - rb * 10;
            *(unsigned short*)(lds + VT_OFF + vd * VT_STR + rb * 32 + jr * 2) = val;
          }
        }
      }
    __syncthreads();

    // ======== attention: each wave owns 4 problems (b = 2wv,2wv+1; hh = 0,1) ========
    {
      const int m = lane & 15;          // QK: A-row (i) / B-col (j)
      const int kq = lane >> 4;         // 0..3
      const int kg = lane >> 5;         // 0..1
      const int dcol = lane & 31;
      float pn[4][4];

      // --- QK + bias + shuffle-softmax ---
      #pragma unroll
      for (int q = 0; q < 4; ++q) {
        const int b = wv * 2 + (q >> 1);
        const int hh = q & 1;
        const int h = p * 2 + hh;
        const int arow = b * 10 + m;                  // >=80 rows: garbage, discarded
        const int chq = ((hh * 4 + kq) ^ (arow & 7)) * 16;
        bf16x8 aq = *(const bf16x8*)(lds + SP_OFF + arow * 256 + chq);
        bf16x8 bk = *(const bf16x8*)(lds + SP_OFF + arow * 256 + 128 + chq);
        f32x4 S = (f32x4){0.f, 0.f, 0.f, 0.f};
        S = __builtin_amdgcn_mfma_f32_16x16x32_bf16(aq, bk, S, 0, 0, 0);
        const int rj = rl[min(arow, 79)];
        #pragma unroll
        for (int jj = 0; jj < 4; ++jj) {
          const int i = kq * 4 + jj;
          const int ri = rl[min(b * 10 + i, 79)];
          float s = S[jj] * 0.17677669529663687f + bf2f(bp[h * 100 + ri * 10 + rj]);
          if (m >= 10) s = -1e30f;                    // mask invalid j
          float mx = s;
          mx = fmaxf(mx, __shfl_xor(mx, 1));
          mx = fmaxf(mx, __shfl_xor(mx, 2));
          mx = fmaxf(mx, __shfl_xor(mx, 4));
          mx = fmaxf(mx, __shfl_xor(mx, 8));
          float e = __expf(s - mx);                   // masked -> exactly 0
          float sm = e;
          sm += __shfl_xor(sm, 1);
          sm += __shfl_xor(sm, 2);
          sm += __shfl_xor(sm, 4);
          sm += __shfl_xor(sm, 8);
          pn[q][jj] = e / sm;
        }
      }
      // --- P-store + PV + direct global O-store ---
      #pragma unroll
      for (int q = 0; q < 4; ++q) {
        const int b = wv * 2 + (q >> 1);
        const int hh = q & 1;
        const int h = p * 2 + hh;
        #pragma unroll
        for (int jj = 0; jj < 4; ++jj) {
          const int i = kq * 4 + jj;
          if (i < 10)
            *(unsigned short*)(lds + PT_OFF + wv * 320 + i * 32 + m * 2) = f2bf(pn[q][jj]);
        }
        f32x16 zero16;
        #pragma unroll
        for (int r = 0; r < 16; ++r) zero16[r] = 0.f;
        // PV: O[i][d] = sum_j P[i][j] * V[b*10+j][hh*32+d]
        bf16x8 pa = *(const bf16x8*)(lds + PT_OFF + wv * 320 + dcol * 32 + kg * 16);
        bf16x8 vb = *(const bf16x8*)(lds + VT_OFF + (hh * 32 + dcol) * VT_STR + b * 32 + kg * 16);
        f32x16 O = __builtin_amdgcn_mfma_f32_32x32x16_bf16(pa, vb, zero16, 0, 0, 0);
        #pragma unroll
        for (int r = 0; r < 6; ++r) {                 // valid output rows only
          const int i = (r & 3) + 8 * (r >> 2) + 4 * kg;
          if (r < 4 || kg == 0) {
            attn_out[(c0 + b * 10 + i) * 256 + h * 32 + dcol] =
                __float2bfloat16(O[r]);
          }
        }
      }
    }
    __syncthreads();
  }
}

// ---------------- WO GEMM: out[M][256] fp32 = attn_out[M][256]bf16 @ WO ----------------
// BM=64, full N=256, BK=64 x 4 steps. A-tile 8 KB LDS; B-frags from L2.
__global__ __launch_bounds__(256) void gemm_wo2_kernel(
    const __hip_bfloat16* __restrict__ A, const __hip_bfloat16* __restrict__ wt,
    float* __restrict__ C)
{
  __shared__ __align__(16) char As2[8192];
  const int t = threadIdx.x;
  const int lane = t & 63;
  const int wv = t >> 6;
  const int g = lane >> 4, cx = lane & 15;
  const size_t m0 = (size_t)blockIdx.x * 64;
  const __hip_bfloat16* WOT = wt + 3 * 65536;

  f32x4 acc[4][4];
  #pragma unroll
  for (int a = 0; a < 4; ++a)
    #pragma unroll
    for (int b = 0; b < 4; ++b) acc[a][b] = (f32x4){0.f, 0.f, 0.f, 0.f};

  #pragma unroll 1
  for (int ks = 0; ks < 4; ++ks) {
    if (ks) __syncthreads();
    #pragma unroll
    for (int c = 0; c < 2; ++c) {
      const int idx = c * 256 + t;          // 0..511 over (row, chunk)
      const int row = idx >> 3, ch = idx & 7;
      uint4 raw = *(const uint4*)(A + (m0 + row) * 256 + ks * 64 + ch * 8);
      *(uint4*)(As2 + row * 128 + ((ch ^ (row & 7)) * 16)) = raw;
    }
    __syncthreads();
    #pragma unroll
    for (int kk = 0; kk < 2; ++kk) {
      bf16x8 bfr[4];
      #pragma unroll
      for (int nf = 0; nf < 4; ++nf) {
        const int n = wv * 64 + nf * 16 + cx;
        bfr[nf] = *(const bf16x8*)(WOT + n * 256 + ks * 64 + kk * 32 + g * 8);
      }
      bf16x8 afr[4];
      #pragma unroll
      for (int mi = 0; mi < 4; ++mi) {
        const int row = mi * 16 + cx;
        const int ch = (kk * 4 + g) ^ (row & 7);
        afr[mi] = *(const bf16x8*)(As2 + row * 128 + ch * 16);
      }
      #pragma unroll
      for (int mi = 0; mi < 4; ++mi)
        #pragma unroll
        for (int nf = 0; nf < 4; ++nf)
          acc[mi][nf] = __builtin_amdgcn_mfma_f32_16x16x32_bf16(afr[mi], bfr[nf], acc[mi][nf], 0, 0, 0);
    }
  }
  #pragma unroll
  for (int mi = 0; mi < 4; ++mi)
    #pragma unroll
    for (int nf = 0; nf < 4; ++nf)
      #pragma unroll
      for (int jj = 0; jj < 4; ++jj) {
        const size_t row = m0 + mi * 16 + g * 4 + jj;
        const int col = wv * 64 + nf * 16 + cx;
        C[row * 256 + col] = acc[mi][nf][jj];
      }
}

extern "C" void kernel_launch(void* const* d_in, const int* in_sizes, int n_in,
                              void* d_out, int out_size, void* d_ws, size_t ws_size,
                              hipStream_t stream)
{
  const float* Z     = (const float*)d_in[0];
  const int*   roles = (const int*)d_in[1];
  const float* WQ    = (const float*)d_in[2];
  const float* WK    = (const float*)d_in[3];
  const float* WV    = (const float*)d_in[4];
  const float* WO    = (const float*)d_in[5];
  const float* Bp    = (const float*)d_in[6];
  float* out = (float*)d_out;

  const long M = 163840;                         // 16384 batches * 10 rows
  char* ws = (char*)d_ws;
  __hip_bfloat16* wt = (__hip_bfloat16*)ws;
  const size_t WT_BYTES = 4u * 256u * 256u * 2u; // 512 KiB
  __hip_bfloat16* attn_ws = (__hip_bfloat16*)(ws + WT_BYTES);

  // chunking (attn_out row = 512 B); chunk multiple of 320 = lcm(80, 64)
  size_t avail = (ws_size > WT_BYTES) ? (ws_size - WT_BYTES) : 0;
  long rows_fit = (long)(avail / 512);
  long chunk = (rows_fit / 320) * 320;
  if (chunk > M) chunk = M;
  if (chunk < 320) chunk = 320;

  prep_wt_kernel<<<256, 256, 0, stream>>>(WQ, WK, WV, WO, wt);

  for (long r0 = 0; r0 < M; r0 += chunk) {
    long rows = M - r0;
    if (rows > chunk) rows = chunk;
    fused_qkv_attn_kernel<<<(int)(rows / 80), 256, 0, stream>>>(
        Z + r0 * 256, wt, roles + r0, Bp, attn_ws);
    gemm_wo2_kernel<<<(int)(rows / 64), 256, 0, stream>>>(
        attn_ws, wt, out + r0 * 256);
  }
}